// Round 8
// baseline (321.648 us; speedup 1.0000x reference)
//
#include <hip/hip_runtime.h>
#include <cstdint>

#define CC 32
#define DD 9
#define CD 288   // C*D
#define BB 8
#define HH 64
#define ZZ 4
#define NB 8     // nodes per block in node-side kernels

__device__ __forceinline__ float silu_f(float v) {
  return v / (1.0f + __expf(-v));
}

__device__ __forceinline__ int blk_of(int d) { return d == 0 ? 0 : (d < 4 ? 1 : 2); }

__global__ __launch_bounds__(256) void k_zero(float* __restrict__ p, int n) {
  int i = blockIdx.x * 256 + threadIdx.x;
  if (i < n) p[i] = 0.0f;
}

// ---------------- CSR build ----------------
__global__ __launch_bounds__(256) void k_hist(const int* __restrict__ edst,
                                              int* __restrict__ deg, int E) {
  int e = blockIdx.x * 256 + threadIdx.x;
  if (e < E) atomicAdd(&deg[edst[e]], 1);
}

__global__ __launch_bounds__(1024) void k_scan(const int* __restrict__ deg,
                                               int* __restrict__ offs,
                                               int* __restrict__ cursor, int N) {
  __shared__ int part[1024];
  int t = threadIdx.x;
  int chunk = (N + 1023) >> 10;
  int base = t * chunk;
  int lim = N - base; if (lim > chunk) lim = chunk; if (lim < 0) lim = 0;
  int s = 0;
  for (int i = 0; i < lim; ++i) s += deg[base + i];
  part[t] = s;
  __syncthreads();
  for (int off = 1; off < 1024; off <<= 1) {
    int v = part[t];
    int u = (t >= off) ? part[t - off] : 0;
    __syncthreads();
    part[t] = v + u;
    __syncthreads();
  }
  int run = (t == 0) ? 0 : part[t - 1];
  for (int i = 0; i < lim; ++i) {
    offs[base + i] = run;
    cursor[base + i] = run;
    run += deg[base + i];
  }
  if (t == 1023) offs[N] = run;
}

__global__ __launch_bounds__(256) void k_scatter(const int* __restrict__ edst,
                                                 int* __restrict__ cursor,
                                                 int* __restrict__ eidx, int E) {
  int e = blockIdx.x * 256 + threadIdx.x;
  if (e < E) {
    int d = edst[e];
    int pos = atomicAdd(&cursor[d], 1);
    eidx[pos] = e;
  }
}

// ---------------- transpose W2 (one-shot, 16 blocks) ----------------
__global__ __launch_bounds__(256) void k_w2t(const float* __restrict__ W2,
                                             float* __restrict__ W2T) {
  int t = blockIdx.x * 256 + threadIdx.x;   // t = q*64 + k
  int q = t >> 6, k = t & 63;
  W2T[t] = W2[k * HH + q];
}

// ---------------- linear_up: NB nodes per block, one batch per block ----------------
__global__ __launch_bounds__(288) void k_linear_up(
    const float* __restrict__ nf, const float* __restrict__ Wup,
    float* __restrict__ x, int N) {
  __shared__ float snf[NB][DD * 36];
  int t = threadIdx.x;
  int g = t >> 5, q = t & 31;
  int tc = t / 9, td = t - tc * 9;
  int l0 = blk_of(g);
  float wcol[CC];
#pragma unroll
  for (int c = 0; c < CC; ++c) wcol[c] = Wup[l0 * 1024 + c * 32 + q];
  int n0 = blockIdx.x * NB;
#pragma unroll
  for (int nb = 0; nb < NB; ++nb) {
    if (n0 + nb < N) snf[nb][td * 36 + tc] = nf[(size_t)(n0 + nb) * CD + t];
  }
  __syncthreads();
#pragma unroll
  for (int nb = 0; nb < NB; ++nb) {
    if (n0 + nb >= N) break;
    const float4* rowp = (const float4*)(snf[nb] + g * 36);
    float a0 = 0.f, a1 = 0.f;
#pragma unroll
    for (int c4 = 0; c4 < 8; ++c4) {
      float4 b = rowp[c4];
      a0 += b.x * wcol[c4 * 4 + 0] + b.y * wcol[c4 * 4 + 1];
      a1 += b.z * wcol[c4 * 4 + 2] + b.w * wcol[c4 * 4 + 3];
    }
    x[(size_t)(n0 + nb) * CD + t] = a0 + a1;
  }
}

// ---------------- radial MLP: small q-loop, static register indices ----------------
__global__ __launch_bounds__(256) void k_mlp(
    const float* __restrict__ ef, const float* __restrict__ cut,
    const float* __restrict__ W1, const float* __restrict__ W2T,
    const float* __restrict__ W3, float* __restrict__ w, int E) {
  int e = blockIdx.x * 256 + threadIdx.x;
  if (e >= E) return;
  const float4* efp = (const float4*)(ef + (size_t)e * BB);
  float4 efa = efp[0];
  float4 efb = efp[1];
  float efv[BB] = {efa.x, efa.y, efa.z, efa.w, efb.x, efb.y, efb.z, efb.w};
  float h1[HH];
#pragma unroll
  for (int q = 0; q < HH; ++q) {
    float a = 0.f;
#pragma unroll
    for (int k = 0; k < BB; ++k) a += efv[k] * W1[k * HH + q];
    h1[q] = silu_f(a);
  }
  float wacc[CC];
#pragma unroll
  for (int c = 0; c < CC; ++c) wacc[c] = 0.f;
  for (int q = 0; q < HH; ++q) {
    const float* r2 = W2T + q * HH;   // contiguous row, uniform -> s_load_dwordx16
    float a0 = 0.f, a1 = 0.f, a2 = 0.f, a3 = 0.f;
#pragma unroll
    for (int k = 0; k < HH; k += 4) {
      a0 += h1[k + 0] * r2[k + 0];
      a1 += h1[k + 1] * r2[k + 1];
      a2 += h1[k + 2] * r2[k + 2];
      a3 += h1[k + 3] * r2[k + 3];
    }
    float h2 = silu_f((a0 + a1) + (a2 + a3));
    const float* r3 = W3 + q * CC;    // contiguous row, uniform -> s_load
#pragma unroll
    for (int c = 0; c < CC; ++c) wacc[c] += h2 * r3[c];
  }
  float cv = cut[e];
  float4* wp = (float4*)(w + (size_t)e * CC);
#pragma unroll
  for (int i = 0; i < 8; ++i) {
    float4 v;
    v.x = wacc[i * 4 + 0] * cv;
    v.y = wacc[i * 4 + 1] * cv;
    v.z = wacc[i * 4 + 2] * cv;
    v.w = wacc[i * 4 + 3] * cv;
    wp[i] = v;
  }
}

// ---------------- gather: one wave per node, halves split even/odd edges ----------------
__global__ __launch_bounds__(256) void k_gather(
    const float* __restrict__ x, const float* __restrict__ w,
    const float* __restrict__ esh, const float* __restrict__ CG,
    const int* __restrict__ offs, const int* __restrict__ eidx,
    const int* __restrict__ esrc, float* __restrict__ mpre, int N) {
  int wid = (blockIdx.x * 256 + threadIdx.x) >> 6;
  if (wid >= N) return;
  int lane = threadIdx.x & 63;
  int h = lane >> 5, c = lane & 31;
  int beg = offs[wid], end = offs[wid + 1];
  float P[81];
#pragma unroll
  for (int i = 0; i < 81; ++i) P[i] = 0.f;
  for (int p0 = beg; p0 < end; p0 += 2) {
    int p = p0 + h;
    bool ok = p < end;
    int pp = ok ? p : p0;
    int e = eidx[pp];
    int s = esrc[e];
    float wc = ok ? w[(size_t)e * CC + c] : 0.f;
    const float* shp = esh + (size_t)e * DD;
    float sh[DD];
#pragma unroll
    for (int j = 0; j < DD; ++j) sh[j] = shp[j];
    const float* xp = x + (size_t)s * CD + c;
    float xs[DD];
#pragma unroll
    for (int i = 0; i < DD; ++i) xs[i] = xp[i * 32];
#pragma unroll
    for (int i = 0; i < DD; ++i) {
      float t = wc * xs[i];
#pragma unroll
      for (int j = 0; j < DD; ++j) P[i * DD + j] += t * sh[j];
    }
  }
  float m[DD];
#pragma unroll
  for (int k = 0; k < DD; ++k) m[k] = 0.f;
#pragma unroll
  for (int i = 0; i < DD; ++i) {
#pragma unroll
    for (int j = 0; j < DD; ++j) {
      float p = P[i * DD + j];
#pragma unroll
      for (int k = 0; k < DD; ++k) m[k] += p * CG[i * 81 + j * DD + k];
    }
  }
#pragma unroll
  for (int k = 0; k < DD; ++k) m[k] += __shfl_xor(m[k], 32);
  if (h == 0) {
    float* mp = mpre + (size_t)wid * CD + c;
#pragma unroll
    for (int k = 0; k < DD; ++k) mp[k * 32] = m[k];
  }
}

// ---------------- fused output: NB nodes per block, one batch per block ----------------
__global__ __launch_bounds__(288) void k_out(
    const float* __restrict__ attrs, const float* __restrict__ Wlin,
    const float* __restrict__ Wsc,
    float* __restrict__ out1, float* __restrict__ out2, int N) {
  __shared__ float smp[NB][CD];     // mpre [d][c]
  __shared__ float smt[NB][CD];     // m_i  [d][c]
  __shared__ float sres1[NB * CD];  // out1 bounce [nb][c][d]
  __shared__ float sres2[NB * CD];  // out2 bounce [nb][c][d]
  int t = threadIdx.x;
  int g = t >> 5, q = t & 31;
  int l0 = blk_of(g);
  float wl[CC];
#pragma unroll
  for (int c = 0; c < CC; ++c) wl[c] = Wlin[l0 * 1024 + c * 32 + q];
  float ws0[CC], ws1[CC], ws2[CC], ws3[CC];
#pragma unroll
  for (int c = 0; c < CC; ++c) {
    ws0[c] = Wsc[0 * 3072 + l0 * 1024 + c * 32 + q];
    ws1[c] = Wsc[1 * 3072 + l0 * 1024 + c * 32 + q];
    ws2[c] = Wsc[2 * 3072 + l0 * 1024 + c * 32 + q];
    ws3[c] = Wsc[3 * 3072 + l0 * 1024 + c * 32 + q];
  }
  int n0 = blockIdx.x * NB;
  float4 av[NB];
#pragma unroll
  for (int nb = 0; nb < NB; ++nb) {
    if (n0 + nb < N) {
      smp[nb][t] = out2[(size_t)(n0 + nb) * CD + t];   // mpre, coalesced
      av[nb] = ((const float4*)attrs)[n0 + nb];
    }
  }
  __syncthreads();
  // einsum1 for all NB nodes
#pragma unroll
  for (int nb = 0; nb < NB; ++nb) {
    if (n0 + nb >= N) break;
    const float4* rowp = (const float4*)(smp[nb] + g * 32);
    float b0 = 0.f, b1 = 0.f;
#pragma unroll
    for (int c4 = 0; c4 < 8; ++c4) {
      float4 b = rowp[c4];
      b0 += b.x * wl[c4 * 4 + 0] + b.y * wl[c4 * 4 + 1];
      b1 += b.z * wl[c4 * 4 + 2] + b.w * wl[c4 * 4 + 3];
    }
    float v = (b0 + b1) * (1.0f / 16.0f);
    smt[nb][t] = v;
    sres1[nb * CD + q * DD + g] = v;   // 9 coprime 32 -> conflict-free
  }
  __syncthreads();
  // einsum2 for all NB nodes
#pragma unroll
  for (int nb = 0; nb < NB; ++nb) {
    if (n0 + nb >= N) break;
    const float4* rowp = (const float4*)(smt[nb] + g * 32);
    float z0 = 0.f, z1 = 0.f, z2 = 0.f, z3 = 0.f;
#pragma unroll
    for (int c4 = 0; c4 < 8; ++c4) {
      float4 b = rowp[c4];
#pragma unroll
      for (int j = 0; j < 4; ++j) {
        float bv = (j == 0) ? b.x : (j == 1) ? b.y : (j == 2) ? b.z : b.w;
        int c = c4 * 4 + j;
        z0 += bv * ws0[c];
        z1 += bv * ws1[c];
        z2 += bv * ws2[c];
        z3 += bv * ws3[c];
      }
    }
    float4 a = av[nb];
    sres2[nb * CD + q * DD + g] = a.x * z0 + a.y * z1 + a.z * z2 + a.w * z3;
  }
  __syncthreads();
  // stores: NB*72 float4 per buffer, 288 threads -> 2 each
#pragma unroll
  for (int r = 0; r < (NB * 72) / 288; ++r) {
    int s = r * 288 + t;
    int nb = s / 72, idx = s - nb * 72;
    if (n0 + nb < N) {
      ((float4*)(out1 + (size_t)(n0 + nb) * CD))[idx] = ((const float4*)sres1)[s];
      ((float4*)(out2 + (size_t)(n0 + nb) * CD))[idx] = ((const float4*)sres2)[s];
    }
  }
}

extern "C" void kernel_launch(void* const* d_in, const int* in_sizes, int n_in,
                              void* d_out, int out_size, void* d_ws, size_t ws_size,
                              hipStream_t stream) {
  const float* nf    = (const float*)d_in[0];
  const float* attrs = (const float*)d_in[1];
  const float* ef    = (const float*)d_in[2];
  const float* esh   = (const float*)d_in[3];
  const float* cutv  = (const float*)d_in[4];
  const float* Wup   = (const float*)d_in[5];
  const float* W1    = (const float*)d_in[6];
  const float* W2    = (const float*)d_in[7];
  const float* W3    = (const float*)d_in[8];
  const float* Wlin  = (const float*)d_in[9];
  const float* Wsc   = (const float*)d_in[10];
  const float* CG    = (const float*)d_in[11];
  const int* esrc    = (const int*)d_in[12];
  const int* edst    = (const int*)d_in[13];
  int N = in_sizes[0] / CD;
  int E = in_sizes[12];
  float* out1 = (float*)d_out;
  float* out2 = out1 + (size_t)N * CD;   // doubles as the m_pre accumulator

  float* x    = (float*)d_ws;                      // N*288 f32
  float* w    = x + (size_t)N * CD;                // E*32 f32
  int* deg    = (int*)(w + (size_t)E * CC);        // N
  int* offs   = deg + N;                           // N+1
  int* cursor = offs + N + 1;                      // N
  int* eidx   = cursor + N;                        // E
  float* W2T  = (float*)(eidx + E);                // 4096 f32

  int nblk = (N + NB - 1) / NB;
  k_zero<<<(N + 255) / 256, 256, 0, stream>>>((float*)deg, N);
  k_hist<<<(E + 255) / 256, 256, 0, stream>>>(edst, deg, E);
  k_scan<<<1, 1024, 0, stream>>>(deg, offs, cursor, N);
  k_scatter<<<(E + 255) / 256, 256, 0, stream>>>(edst, cursor, eidx, E);
  k_w2t<<<16, 256, 0, stream>>>(W2, W2T);
  k_linear_up<<<nblk, 288, 0, stream>>>(nf, Wup, x, N);
  k_mlp<<<(E + 255) / 256, 256, 0, stream>>>(ef, cutv, W1, W2T, W3, w, E);
  k_gather<<<(N + 3) / 4, 256, 0, stream>>>(x, w, esh, CG, offs, eidx, esrc, out2, N);
  k_out<<<nblk, 288, 0, stream>>>(attrs, Wlin, Wsc, out1, out2, N);
}

// Round 9
// 286.736 us; speedup vs baseline: 1.1218x; 1.1218x over previous
//
#include <hip/hip_runtime.h>
#include <cstdint>

#define CC 32
#define DD 9
#define CD 288   // C*D
#define BB 8
#define HH 64
#define ZZ 4
#define NB 8     // nodes per batch in node-side kernels

__device__ __forceinline__ float silu_f(float v) {
  return v / (1.0f + __expf(-v));
}

__device__ __forceinline__ int blk_of(int d) { return d == 0 ? 0 : (d < 4 ? 1 : 2); }

__global__ __launch_bounds__(256) void k_zero(float* __restrict__ p, int n) {
  int i = blockIdx.x * 256 + threadIdx.x;
  if (i < n) p[i] = 0.0f;
}

// ---------------- CSR build ----------------
__global__ __launch_bounds__(256) void k_hist(const int* __restrict__ edst,
                                              int* __restrict__ deg, int E) {
  int e = blockIdx.x * 256 + threadIdx.x;
  if (e < E) atomicAdd(&deg[edst[e]], 1);
}

__global__ __launch_bounds__(1024) void k_scan(const int* __restrict__ deg,
                                               int* __restrict__ offs,
                                               int* __restrict__ cursor, int N) {
  __shared__ int part[1024];
  int t = threadIdx.x;
  int chunk = (N + 1023) >> 10;
  int base = t * chunk;
  int lim = N - base; if (lim > chunk) lim = chunk; if (lim < 0) lim = 0;
  int s = 0;
  for (int i = 0; i < lim; ++i) s += deg[base + i];
  part[t] = s;
  __syncthreads();
  for (int off = 1; off < 1024; off <<= 1) {
    int v = part[t];
    int u = (t >= off) ? part[t - off] : 0;
    __syncthreads();
    part[t] = v + u;
    __syncthreads();
  }
  int run = (t == 0) ? 0 : part[t - 1];
  for (int i = 0; i < lim; ++i) {
    offs[base + i] = run;
    cursor[base + i] = run;
    run += deg[base + i];
  }
  if (t == 1023) offs[N] = run;
}

__global__ __launch_bounds__(256) void k_scatter(const int* __restrict__ edst,
                                                 int* __restrict__ cursor,
                                                 int* __restrict__ eidx, int E) {
  int e = blockIdx.x * 256 + threadIdx.x;
  if (e < E) {
    int d = edst[e];
    int pos = atomicAdd(&cursor[d], 1);
    eidx[pos] = e;
  }
}

// ---------------- transpose W2 (one-shot, 16 blocks) ----------------
__global__ __launch_bounds__(256) void k_w2t(const float* __restrict__ W2,
                                             float* __restrict__ W2T) {
  int t = blockIdx.x * 256 + threadIdx.x;   // t = q*64 + k
  int q = t >> 6, k = t & 63;
  W2T[t] = W2[k * HH + q];
}

// ---------------- linear_up: NB nodes per block, one batch per block ----------------
__global__ __launch_bounds__(288) void k_linear_up(
    const float* __restrict__ nf, const float* __restrict__ Wup,
    float* __restrict__ x, int N) {
  __shared__ float snf[NB][DD * 36];
  int t = threadIdx.x;
  int g = t >> 5, q = t & 31;
  int tc = t / 9, td = t - tc * 9;
  int l0 = blk_of(g);
  float wcol[CC];
#pragma unroll
  for (int c = 0; c < CC; ++c) wcol[c] = Wup[l0 * 1024 + c * 32 + q];
  int n0 = blockIdx.x * NB;
#pragma unroll
  for (int nb = 0; nb < NB; ++nb) {
    if (n0 + nb < N) snf[nb][td * 36 + tc] = nf[(size_t)(n0 + nb) * CD + t];
  }
  __syncthreads();
#pragma unroll
  for (int nb = 0; nb < NB; ++nb) {
    if (n0 + nb >= N) break;
    const float4* rowp = (const float4*)(snf[nb] + g * 36);
    float a0 = 0.f, a1 = 0.f;
#pragma unroll
    for (int c4 = 0; c4 < 8; ++c4) {
      float4 b = rowp[c4];
      a0 += b.x * wcol[c4 * 4 + 0] + b.y * wcol[c4 * 4 + 1];
      a1 += b.z * wcol[c4 * 4 + 2] + b.w * wcol[c4 * 4 + 3];
    }
    x[(size_t)(n0 + nb) * CD + t] = a0 + a1;
  }
}

// ---------------- radial MLP: small q-loop; launch_bounds(256,2) so h1 stays in VGPRs ----------------
__global__ __launch_bounds__(256, 2) void k_mlp(
    const float* __restrict__ ef, const float* __restrict__ cut,
    const float* __restrict__ W1, const float* __restrict__ W2T,
    const float* __restrict__ W3, float* __restrict__ w, int E) {
  int e = blockIdx.x * 256 + threadIdx.x;
  if (e >= E) return;
  const float4* efp = (const float4*)(ef + (size_t)e * BB);
  float4 efa = efp[0];
  float4 efb = efp[1];
  float efv[BB] = {efa.x, efa.y, efa.z, efa.w, efb.x, efb.y, efb.z, efb.w};
  float h1[HH];
#pragma unroll
  for (int q = 0; q < HH; ++q) {
    float a = 0.f;
#pragma unroll
    for (int k = 0; k < BB; ++k) a += efv[k] * W1[k * HH + q];
    h1[q] = silu_f(a);
  }
  float wacc[CC];
#pragma unroll
  for (int c = 0; c < CC; ++c) wacc[c] = 0.f;
  for (int q = 0; q < HH; ++q) {
    const float* r2 = W2T + q * HH;   // contiguous row, uniform -> s_load_dwordx16
    float a0 = 0.f, a1 = 0.f, a2 = 0.f, a3 = 0.f;
#pragma unroll
    for (int k = 0; k < HH; k += 4) {
      a0 += h1[k + 0] * r2[k + 0];
      a1 += h1[k + 1] * r2[k + 1];
      a2 += h1[k + 2] * r2[k + 2];
      a3 += h1[k + 3] * r2[k + 3];
    }
    float h2 = silu_f((a0 + a1) + (a2 + a3));
    const float* r3 = W3 + q * CC;    // contiguous row, uniform -> s_load
#pragma unroll
    for (int c = 0; c < CC; ++c) wacc[c] += h2 * r3[c];
  }
  float cv = cut[e];
  float4* wp = (float4*)(w + (size_t)e * CC);
#pragma unroll
  for (int i = 0; i < 8; ++i) {
    float4 v;
    v.x = wacc[i * 4 + 0] * cv;
    v.y = wacc[i * 4 + 1] * cv;
    v.z = wacc[i * 4 + 2] * cv;
    v.w = wacc[i * 4 + 3] * cv;
    wp[i] = v;
  }
}

// ---------------- gather: one wave per node, halves split even/odd edges ----------------
__global__ __launch_bounds__(256) void k_gather(
    const float* __restrict__ x, const float* __restrict__ w,
    const float* __restrict__ esh, const float* __restrict__ CG,
    const int* __restrict__ offs, const int* __restrict__ eidx,
    const int* __restrict__ esrc, float* __restrict__ mpre, int N) {
  int wid = (blockIdx.x * 256 + threadIdx.x) >> 6;
  if (wid >= N) return;
  int lane = threadIdx.x & 63;
  int h = lane >> 5, c = lane & 31;
  int beg = offs[wid], end = offs[wid + 1];
  float P[81];
#pragma unroll
  for (int i = 0; i < 81; ++i) P[i] = 0.f;
  for (int p0 = beg; p0 < end; p0 += 2) {
    int p = p0 + h;
    bool ok = p < end;
    int pp = ok ? p : p0;
    int e = eidx[pp];
    int s = esrc[e];
    float wc = ok ? w[(size_t)e * CC + c] : 0.f;
    const float* shp = esh + (size_t)e * DD;
    float sh[DD];
#pragma unroll
    for (int j = 0; j < DD; ++j) sh[j] = shp[j];
    const float* xp = x + (size_t)s * CD + c;
    float xs[DD];
#pragma unroll
    for (int i = 0; i < DD; ++i) xs[i] = xp[i * 32];
#pragma unroll
    for (int i = 0; i < DD; ++i) {
      float t = wc * xs[i];
#pragma unroll
      for (int j = 0; j < DD; ++j) P[i * DD + j] += t * sh[j];
    }
  }
  float m[DD];
#pragma unroll
  for (int k = 0; k < DD; ++k) m[k] = 0.f;
#pragma unroll
  for (int i = 0; i < DD; ++i) {
#pragma unroll
    for (int j = 0; j < DD; ++j) {
      float p = P[i * DD + j];
#pragma unroll
      for (int k = 0; k < DD; ++k) m[k] += p * CG[i * 81 + j * DD + k];
    }
  }
#pragma unroll
  for (int k = 0; k < DD; ++k) m[k] += __shfl_xor(m[k], 32);
  if (h == 0) {
    float* mp = mpre + (size_t)wid * CD + c;
#pragma unroll
    for (int k = 0; k < DD; ++k) mp[k * 32] = m[k];
  }
}

// ---------------- fused output: persistent blocks, batch prefetch ----------------
// grid 512 blocks x 288 threads; each block loops over node batches of NB,
// prefetching the next batch's mpre into registers under current compute.
__global__ __launch_bounds__(288, 1) void k_out(
    const float* __restrict__ attrs, const float* __restrict__ Wlin,
    const float* __restrict__ Wsc,
    float* __restrict__ out1, float* __restrict__ out2, int N) {
  __shared__ float smp[NB][CD];     // mpre [d][c]
  __shared__ float smt[NB][CD];     // m_i  [d][c]
  __shared__ float sres1[NB * CD];  // out1 bounce [nb][c][d]
  __shared__ float sres2[NB * CD];  // out2 bounce [nb][c][d]
  int t = threadIdx.x;
  int g = t >> 5, q = t & 31;
  int l0 = blk_of(g);
  float wl[CC];
#pragma unroll
  for (int c = 0; c < CC; ++c) wl[c] = Wlin[l0 * 1024 + c * 32 + q];
  float ws0[CC], ws1[CC], ws2[CC], ws3[CC];
#pragma unroll
  for (int c = 0; c < CC; ++c) {
    ws0[c] = Wsc[0 * 3072 + l0 * 1024 + c * 32 + q];
    ws1[c] = Wsc[1 * 3072 + l0 * 1024 + c * 32 + q];
    ws2[c] = Wsc[2 * 3072 + l0 * 1024 + c * 32 + q];
    ws3[c] = Wsc[3 * 3072 + l0 * 1024 + c * 32 + q];
  }
  int nbat = (N + NB - 1) / NB;
  int b = blockIdx.x;
  float r[NB];
  if (b < nbat) {
#pragma unroll
    for (int nb = 0; nb < NB; ++nb) r[nb] = out2[(size_t)(b * NB + nb) * CD + t];
  }
  for (; b < nbat; b += gridDim.x) {
    int n0 = b * NB;
    __syncthreads();                 // prev-iter smp/smt/sres reads done
#pragma unroll
    for (int nb = 0; nb < NB; ++nb) smp[nb][t] = r[nb];
    // attrs for current batch (broadcast loads; latency hidden under e1)
    float4 av[NB];
#pragma unroll
    for (int nb = 0; nb < NB; ++nb) av[nb] = ((const float4*)attrs)[n0 + nb];
    __syncthreads();
    // prefetch next batch's mpre (in flight across e1/e2)
    int b2 = b + gridDim.x;
    if (b2 < nbat) {
#pragma unroll
      for (int nb = 0; nb < NB; ++nb) r[nb] = out2[(size_t)(b2 * NB + nb) * CD + t];
    }
    // einsum1 for all NB nodes
#pragma unroll
    for (int nb = 0; nb < NB; ++nb) {
      const float4* rowp = (const float4*)(smp[nb] + g * 32);
      float b0 = 0.f, b1 = 0.f;
#pragma unroll
      for (int c4 = 0; c4 < 8; ++c4) {
        float4 bb = rowp[c4];
        b0 += bb.x * wl[c4 * 4 + 0] + bb.y * wl[c4 * 4 + 1];
        b1 += bb.z * wl[c4 * 4 + 2] + bb.w * wl[c4 * 4 + 3];
      }
      float v = (b0 + b1) * (1.0f / 16.0f);
      smt[nb][t] = v;
      sres1[nb * CD + q * DD + g] = v;   // 9 coprime 32 -> conflict-free
    }
    __syncthreads();
    // einsum2 for all NB nodes
#pragma unroll
    for (int nb = 0; nb < NB; ++nb) {
      const float4* rowp = (const float4*)(smt[nb] + g * 32);
      float z0 = 0.f, z1 = 0.f, z2 = 0.f, z3 = 0.f;
#pragma unroll
      for (int c4 = 0; c4 < 8; ++c4) {
        float4 bb = rowp[c4];
#pragma unroll
        for (int j = 0; j < 4; ++j) {
          float bv = (j == 0) ? bb.x : (j == 1) ? bb.y : (j == 2) ? bb.z : bb.w;
          int c = c4 * 4 + j;
          z0 += bv * ws0[c];
          z1 += bv * ws1[c];
          z2 += bv * ws2[c];
          z3 += bv * ws3[c];
        }
      }
      float4 a = av[nb];
      sres2[nb * CD + q * DD + g] = a.x * z0 + a.y * z1 + a.z * z2 + a.w * z3;
    }
    __syncthreads();
    // stores: NB*72 float4 per buffer, 288 threads -> 2 each
#pragma unroll
    for (int rr = 0; rr < (NB * 72) / 288; ++rr) {
      int s = rr * 288 + t;
      int nb = s / 72, idx = s - nb * 72;
      ((float4*)(out1 + (size_t)(n0 + nb) * CD))[idx] = ((const float4*)sres1)[s];
      ((float4*)(out2 + (size_t)(n0 + nb) * CD))[idx] = ((const float4*)sres2)[s];
    }
  }
}

extern "C" void kernel_launch(void* const* d_in, const int* in_sizes, int n_in,
                              void* d_out, int out_size, void* d_ws, size_t ws_size,
                              hipStream_t stream) {
  const float* nf    = (const float*)d_in[0];
  const float* attrs = (const float*)d_in[1];
  const float* ef    = (const float*)d_in[2];
  const float* esh   = (const float*)d_in[3];
  const float* cutv  = (const float*)d_in[4];
  const float* Wup   = (const float*)d_in[5];
  const float* W1    = (const float*)d_in[6];
  const float* W2    = (const float*)d_in[7];
  const float* W3    = (const float*)d_in[8];
  const float* Wlin  = (const float*)d_in[9];
  const float* Wsc   = (const float*)d_in[10];
  const float* CG    = (const float*)d_in[11];
  const int* esrc    = (const int*)d_in[12];
  const int* edst    = (const int*)d_in[13];
  int N = in_sizes[0] / CD;
  int E = in_sizes[12];
  float* out1 = (float*)d_out;
  float* out2 = out1 + (size_t)N * CD;   // doubles as the m_pre accumulator

  float* x    = (float*)d_ws;                      // N*288 f32
  float* w    = x + (size_t)N * CD;                // E*32 f32
  int* deg    = (int*)(w + (size_t)E * CC);        // N
  int* offs   = deg + N;                           // N+1
  int* cursor = offs + N + 1;                      // N
  int* eidx   = cursor + N;                        // E
  float* W2T  = (float*)(eidx + E);                // 4096 f32

  int nblk = (N + NB - 1) / NB;
  k_zero<<<(N + 255) / 256, 256, 0, stream>>>((float*)deg, N);
  k_hist<<<(E + 255) / 256, 256, 0, stream>>>(edst, deg, E);
  k_scan<<<1, 1024, 0, stream>>>(deg, offs, cursor, N);
  k_scatter<<<(E + 255) / 256, 256, 0, stream>>>(edst, cursor, eidx, E);
  k_w2t<<<16, 256, 0, stream>>>(W2, W2T);
  k_linear_up<<<nblk, 288, 0, stream>>>(nf, Wup, x, N);
  k_mlp<<<(E + 255) / 256, 256, 0, stream>>>(ef, cutv, W1, W2T, W3, w, E);
  k_gather<<<(N + 3) / 4, 256, 0, stream>>>(x, w, esh, CG, offs, eidx, esrc, out2, N);
  k_out<<<512, 288, 0, stream>>>(attrs, Wlin, Wsc, out1, out2, N);
}